// Round 8
// baseline (478.061 us; speedup 1.0000x reference)
//
#include <hip/hip_runtime.h>
#include <hip/hip_bf16.h>

// GRU: B=4096, T=512, I=1, H=32, C=2 — MFMA formulation.
// One wave per 16 batches. Per step: gates = [96x32] W_hh  x  [32x16] h
// = 6x v_mfma_f32_16x16x32_f16 (A-frags loop-invariant). x-terms fold into
// the C-operand init (I==1 -> rank-1). h kept in C layout (col=lane&15=batch,
// row=(lane>>4)*4+q); relayout to B-frag (k=8*(lane>>4)+i, col=lane&15) via
// LDS transpose: 2x ds_write_b64 + 1x ds_read_b128, stride-20 (2-way conflicts
// only = free). Single wave per block -> no barriers anywhere.
// Grid 256 x 64thr = 1 wave/CU; latency-chain bound, VALU per batch-step ~19cyc.

typedef _Float16 f16x8 __attribute__((ext_vector_type(8)));
typedef float f32x4 __attribute__((ext_vector_type(4)));

__device__ __forceinline__ int pkf16(float lo, float hi) {
    return __builtin_bit_cast(int, __builtin_amdgcn_cvt_pkrtz(lo, hi));
}

__global__ __launch_bounds__(64)
void gru_mfma_kernel(const float* __restrict__ x,
                     const float* __restrict__ W_ih,
                     const float* __restrict__ W_hh,
                     const float* __restrict__ b_ih,
                     const float* __restrict__ b_hh,
                     const float* __restrict__ fc_w,
                     const float* __restrict__ fc_b,
                     float* __restrict__ out)
{
    const int l   = threadIdx.x;     // 0..63
    const int n   = l & 15;          // batch column (C/D + B col; A row slot)
    const int g   = l >> 4;          // k-group / row-group
    const int bb0 = blockIdx.x * 16;

    __shared__ float x_lds[16 * 36]; // [batch][t-chunk], stride 36 (pad)
    __shared__ int   hB[16 * 20];    // [batch][k-pair pack], stride 20 (pad)

    // ---- A fragments: 6 row-tiles of W96 = [W_hh_r; W_hh_z; W_hh_n] ----
    // A layout: lane supplies A[row = l&15][k = 8*(l>>4) + i], i=0..7.
    auto loadA = [&](int tile) {
        const float* p = W_hh + (size_t)(tile * 16 + n) * 32 + g * 8;
        float4 a = *reinterpret_cast<const float4*>(p);
        float4 b = *reinterpret_cast<const float4*>(p + 4);
        int4 pk;
        pk.x = pkf16(a.x, a.y); pk.y = pkf16(a.z, a.w);
        pk.z = pkf16(b.x, b.y); pk.w = pkf16(b.z, b.w);
        return __builtin_bit_cast(f16x8, pk);
    };
    const f16x8 Ar0 = loadA(0), Ar1 = loadA(1);
    const f16x8 Az0 = loadA(2), Az1 = loadA(3);
    const f16x8 An0 = loadA(4), An1 = loadA(5);

    // ---- per-lane row constants: this lane's rows are d = 16m + 4g + q ----
    auto ld4 = [](const float* p) {
        float4 v = *reinterpret_cast<const float4*>(p);
        f32x4 r; r[0] = v.x; r[1] = v.y; r[2] = v.z; r[3] = v.w; return r;
    };
    const int d0 = 4 * g;
    const f32x4 wihr0 = ld4(W_ih + d0),      wihr1 = ld4(W_ih + 16 + d0);
    const f32x4 wihz0 = ld4(W_ih + 32 + d0), wihz1 = ld4(W_ih + 48 + d0);
    const f32x4 wihn0 = ld4(W_ih + 64 + d0), wihn1 = ld4(W_ih + 80 + d0);
    const f32x4 br0  = ld4(b_ih + d0)      + ld4(b_hh + d0);
    const f32x4 br1  = ld4(b_ih + 16 + d0) + ld4(b_hh + 16 + d0);
    const f32x4 bz0  = ld4(b_ih + 32 + d0) + ld4(b_hh + 32 + d0);
    const f32x4 bz1  = ld4(b_ih + 48 + d0) + ld4(b_hh + 48 + d0);
    const f32x4 bin0 = ld4(b_ih + 64 + d0), bin1 = ld4(b_ih + 80 + d0);
    const f32x4 bhn0 = ld4(b_hh + 64 + d0), bhn1 = ld4(b_hh + 80 + d0);

    // ---- state ----
    f32x4 h0 = {0.f, 0.f, 0.f, 0.f};   // hidden 4g+q     (rows 0..15)
    f32x4 h1 = {0.f, 0.f, 0.f, 0.f};   // hidden 16+4g+q  (rows 16..31)
    f16x8 Bh = {};                     // B fragment of h (zero)

    const float* xrow = x + (size_t)(bb0 + n) * 512 + g * 8;
    {   // stage x chunk 0: lane covers batch n, t in [8g, 8g+8)
        float4 a = *reinterpret_cast<const float4*>(xrow);
        float4 b = *reinterpret_cast<const float4*>(xrow + 4);
        *reinterpret_cast<float4*>(&x_lds[n * 36 + g * 8])     = a;
        *reinterpret_cast<float4*>(&x_lds[n * 36 + g * 8 + 4]) = b;
    }

    for (int c = 0; c < 16; ++c) {
        // prefetch next x chunk into regs (held across the 32 steps)
        const float* nx = xrow + 32 * (c < 15 ? c + 1 : 15);
        float4 pa = *reinterpret_cast<const float4*>(nx);
        float4 pb = *reinterpret_cast<const float4*>(nx + 4);

        #pragma unroll 2
        for (int tt = 0; tt < 32; ++tt) {
            float xv = x_lds[n * 36 + tt];   // x[batch n][t] (broadcast read)

            // C-operand init: fold x-terms + biases (rank-1 since I==1)
            f32x4 cr0, cr1, cz0, cz1;
            f32x4 cn0 = bhn0, cn1 = bhn1;
            #pragma unroll
            for (int q = 0; q < 4; ++q) {
                cr0[q] = fmaf(xv, wihr0[q], br0[q]);
                cr1[q] = fmaf(xv, wihr1[q], br1[q]);
                cz0[q] = fmaf(xv, wihz0[q], bz0[q]);
                cz1[q] = fmaf(xv, wihz1[q], bz1[q]);
            }

            cr0 = __builtin_amdgcn_mfma_f32_16x16x32_f16(Ar0, Bh, cr0, 0, 0, 0);
            cr1 = __builtin_amdgcn_mfma_f32_16x16x32_f16(Ar1, Bh, cr1, 0, 0, 0);
            cz0 = __builtin_amdgcn_mfma_f32_16x16x32_f16(Az0, Bh, cz0, 0, 0, 0);
            cz1 = __builtin_amdgcn_mfma_f32_16x16x32_f16(Az1, Bh, cz1, 0, 0, 0);
            cn0 = __builtin_amdgcn_mfma_f32_16x16x32_f16(An0, Bh, cn0, 0, 0, 0);
            cn1 = __builtin_amdgcn_mfma_f32_16x16x32_f16(An1, Bh, cn1, 0, 0, 0);

            // gates (elementwise on C layout)
            #pragma unroll
            for (int q = 0; q < 4; ++q) {
                float r0 = 1.0f / (1.0f + __expf(-cr0[q]));
                float r1 = 1.0f / (1.0f + __expf(-cr1[q]));
                float z0 = 1.0f / (1.0f + __expf(-cz0[q]));
                float z1 = 1.0f / (1.0f + __expf(-cz1[q]));
                float np0 = fmaf(r0, cn0[q], fmaf(xv, wihn0[q], bin0[q]));
                float np1 = fmaf(r1, cn1[q], fmaf(xv, wihn1[q], bin1[q]));
                float n0 = 1.0f - 2.0f / (1.0f + __expf(2.0f * np0));
                float n1 = 1.0f - 2.0f / (1.0f + __expf(2.0f * np1));
                h0[q] = fmaf(z0, h0[q] - n0, n0);
                h1[q] = fmaf(z1, h1[q] - n1, n1);
            }

            // publish h -> B fragment via LDS transpose (single wave, no barrier)
            // lane owns k-pair packs {2g, 2g+1} (m=0) and {8+2g, 8+2g+1} (m=1)
            int2 w0; w0.x = pkf16(h0[0], h0[1]); w0.y = pkf16(h0[2], h0[3]);
            int2 w1; w1.x = pkf16(h1[0], h1[1]); w1.y = pkf16(h1[2], h1[3]);
            *reinterpret_cast<int2*>(&hB[n * 20 + 2 * g])     = w0;
            *reinterpret_cast<int2*>(&hB[n * 20 + 8 + 2 * g]) = w1;
            // B-frag: lane needs k-pair packs 4g..4g+3 of its batch column
            int4 bh4 = *reinterpret_cast<const int4*>(&hB[n * 20 + 4 * g]);
            Bh = __builtin_bit_cast(f16x8, bh4);
        }

        // store prefetched x chunk for next c (all reads of chunk c are done)
        *reinterpret_cast<float4*>(&x_lds[n * 36 + g * 8])     = pa;
        *reinterpret_cast<float4*>(&x_lds[n * 36 + g * 8 + 4]) = pb;
    }

    // ---- FC epilogue: out[bb0+n][c] = sum_d h[d][n]*fc_w[c][d] + fc_b[c] ----
    const f32x4 f00 = ld4(fc_w + d0),      f01 = ld4(fc_w + 16 + d0);
    const f32x4 f10 = ld4(fc_w + 32 + d0), f11 = ld4(fc_w + 48 + d0);
    float s0 = 0.f, s1 = 0.f;
    #pragma unroll
    for (int q = 0; q < 4; ++q) {
        s0 += h0[q] * f00[q] + h1[q] * f01[q];
        s1 += h0[q] * f10[q] + h1[q] * f11[q];
    }
    s0 += __shfl_xor(s0, 16); s0 += __shfl_xor(s0, 32);
    s1 += __shfl_xor(s1, 16); s1 += __shfl_xor(s1, 32);
    if (l < 16) {
        out[(size_t)(bb0 + n) * 2 + 0] = s0 + fc_b[0];
        out[(size_t)(bb0 + n) * 2 + 1] = s1 + fc_b[1];
    }
}

extern "C" void kernel_launch(void* const* d_in, const int* in_sizes, int n_in,
                              void* d_out, int out_size, void* d_ws, size_t ws_size,
                              hipStream_t stream)
{
    const float* x    = (const float*)d_in[0];
    const float* W_ih = (const float*)d_in[1];
    const float* W_hh = (const float*)d_in[2];
    const float* b_ih = (const float*)d_in[3];
    const float* b_hh = (const float*)d_in[4];
    const float* fc_w = (const float*)d_in[5];
    const float* fc_b = (const float*)d_in[6];
    float* out = (float*)d_out;

    // 4096 batches / 16 per wave = 256 blocks of one 64-lane wave each
    dim3 grid(256), block(64);
    hipLaunchKernelGGL(gru_mfma_kernel, grid, block, 0, stream,
                       x, W_ih, W_hh, b_ih, b_hh, fc_w, fc_b, out);
}

// Round 9
// 223.451 us; speedup vs baseline: 2.1394x; 2.1394x over previous
//
#include <hip/hip_runtime.h>
#include <hip/hip_bf16.h>

// GRU: B=4096, T=512, I=1, H=32, C=2.
// One 32-lane group per batch element (8 groups / 256-thr block, 2048 waves).
// Lane j owns h[j] and W_hh rows {j,32+j,64+j} as 48 int-packed fp16x2 regs.
// h replication via LDS: ds_write_b16(own h as f16) + 4x ds_read_b128 row
// broadcast (single-wave group -> no barrier).
// KEY CHANGE vs R6: __launch_bounds__(256,1) -> 512 unified VGPR+AGPR regs
// per wave, so the 48 weight packs can be ARCH-VGPR-resident without the
// allocator AGPR-izing them (the v_accvgpr shuttle = the 3x VALU inflation).

typedef _Float16 half2v __attribute__((ext_vector_type(2)));

__device__ __forceinline__ float fdot2f(int a, int b, float c) {
    return __builtin_amdgcn_fdot2(__builtin_bit_cast(half2v, a),
                                  __builtin_bit_cast(half2v, b), c, false);
}

__device__ __forceinline__ int pkf16(float lo, float hi) {
    return __builtin_bit_cast(int, __builtin_amdgcn_cvt_pkrtz(lo, hi));
}

#define FOR16(M) M(0) M(1) M(2) M(3) M(4) M(5) M(6) M(7) \
                 M(8) M(9) M(10) M(11) M(12) M(13) M(14) M(15)

__global__ __launch_bounds__(256, 1)
void gru_fused_kernel(const float* __restrict__ x,
                      const float* __restrict__ W_ih,
                      const float* __restrict__ W_hh,
                      const float* __restrict__ b_ih,
                      const float* __restrict__ b_hh,
                      const float* __restrict__ fc_w,
                      const float* __restrict__ fc_b,
                      float* __restrict__ out)
{
    const int tid = threadIdx.x;
    const int j   = tid & 31;                      // hidden index this lane owns
    const int g   = tid >> 5;                      // group (batch slot in block)
    const int bb  = blockIdx.x * 8 + g;            // batch element

    __shared__ unsigned short hbuf[8][32];         // f16 h per group (64B rows)

    // ---- named packed weight registers (48 ints) ----
#define DECLW(p) int wr##p, wz##p, wn##p;
    FOR16(DECLW)
#undef DECLW

    {
        const float4* wrp = reinterpret_cast<const float4*>(W_hh + (j) * 32);
        const float4* wzp = reinterpret_cast<const float4*>(W_hh + (32 + j) * 32);
        const float4* wnp = reinterpret_cast<const float4*>(W_hh + (64 + j) * 32);
#define INITQ(q, p0, p1)                                \
        {                                               \
            float4 a = wrp[q], b = wzp[q], c = wnp[q];  \
            wr##p0 = pkf16(a.x, a.y);                   \
            wr##p1 = pkf16(a.z, a.w);                   \
            wz##p0 = pkf16(b.x, b.y);                   \
            wz##p1 = pkf16(b.z, b.w);                   \
            wn##p0 = pkf16(c.x, c.y);                   \
            wn##p1 = pkf16(c.z, c.w);                   \
        }
        INITQ(0, 0, 1)  INITQ(1, 2, 3)  INITQ(2, 4, 5)  INITQ(3, 6, 7)
        INITQ(4, 8, 9)  INITQ(5, 10, 11) INITQ(6, 12, 13) INITQ(7, 14, 15)
#undef INITQ
    }

    // biases / input weights (I == 1)
    const float br   = b_ih[j]      + b_hh[j];
    const float bz   = b_ih[32 + j] + b_hh[32 + j];
    const float bin  = b_ih[64 + j];
    const float bhn  = b_hh[64 + j];
    const float wihr = W_ih[j];
    const float wihz = W_ih[32 + j];
    const float wihn = W_ih[64 + j];

    const float* xp = x + (size_t)bb * 512;
    float h = 0.0f;
    hbuf[g][j] = 0;                     // f16 +0.0

    float xcur = xp[j];                 // chunk 0 of x

    for (int c = 0; c < 16; ++c) {
        float xnext = xp[((c + 1) & 15) * 32 + j];   // prefetch next chunk

        #pragma unroll 2
        for (int tt = 0; tt < 32; ++tt) {
            // read the whole replicated h row (4 x b128 broadcast reads)
            const int4* hp = reinterpret_cast<const int4*>(&hbuf[g][0]);
            int4 A = hp[0], B = hp[1], C = hp[2], D = hp[3];

            float xb = __shfl(xcur, tt, 32);         // x[bb, 32*c + tt]

            float ar = fmaf(xb, wihr, br);
            float az = fmaf(xb, wihz, bz);
            float an = bhn;
            ar = fdot2f(wr0,  A.x, ar); az = fdot2f(wz0,  A.x, az); an = fdot2f(wn0,  A.x, an);
            ar = fdot2f(wr1,  A.y, ar); az = fdot2f(wz1,  A.y, az); an = fdot2f(wn1,  A.y, an);
            ar = fdot2f(wr2,  A.z, ar); az = fdot2f(wz2,  A.z, az); an = fdot2f(wn2,  A.z, an);
            ar = fdot2f(wr3,  A.w, ar); az = fdot2f(wz3,  A.w, az); an = fdot2f(wn3,  A.w, an);
            ar = fdot2f(wr4,  B.x, ar); az = fdot2f(wz4,  B.x, az); an = fdot2f(wn4,  B.x, an);
            ar = fdot2f(wr5,  B.y, ar); az = fdot2f(wz5,  B.y, az); an = fdot2f(wn5,  B.y, an);
            ar = fdot2f(wr6,  B.z, ar); az = fdot2f(wz6,  B.z, az); an = fdot2f(wn6,  B.z, an);
            ar = fdot2f(wr7,  B.w, ar); az = fdot2f(wz7,  B.w, az); an = fdot2f(wn7,  B.w, an);
            ar = fdot2f(wr8,  C.x, ar); az = fdot2f(wz8,  C.x, az); an = fdot2f(wn8,  C.x, an);
            ar = fdot2f(wr9,  C.y, ar); az = fdot2f(wz9,  C.y, az); an = fdot2f(wn9,  C.y, an);
            ar = fdot2f(wr10, C.z, ar); az = fdot2f(wz10, C.z, az); an = fdot2f(wn10, C.z, an);
            ar = fdot2f(wr11, C.w, ar); az = fdot2f(wz11, C.w, az); an = fdot2f(wn11, C.w, an);
            ar = fdot2f(wr12, D.x, ar); az = fdot2f(wz12, D.x, az); an = fdot2f(wn12, D.x, an);
            ar = fdot2f(wr13, D.y, ar); az = fdot2f(wz13, D.y, az); an = fdot2f(wn13, D.y, an);
            ar = fdot2f(wr14, D.z, ar); az = fdot2f(wz14, D.z, az); an = fdot2f(wn14, D.z, an);
            ar = fdot2f(wr15, D.w, ar); az = fdot2f(wz15, D.w, az); an = fdot2f(wn15, D.w, an);

            float r = 1.0f / (1.0f + __expf(-ar));
            float z = 1.0f / (1.0f + __expf(-az));
            float npre = fmaf(r, an, fmaf(xb, wihn, bin));
            float n = 1.0f - 2.0f / (1.0f + __expf(2.0f * npre));
            h = fmaf(z, h - n, n);       // h = n + z*(h-n)

            // publish new h as f16 for next step's broadcast reads
            hbuf[g][j] = __builtin_bit_cast(unsigned short, (_Float16)h);
        }
        xcur = xnext;
    }

    // ---- FC epilogue: out[bb, c] = sum_j h_j * fc_w[c*32+j] + fc_b[c] ----
    float s0 = h * fc_w[j];
    float s1 = h * fc_w[32 + j];
    #pragma unroll
    for (int off = 16; off >= 1; off >>= 1) {
        s0 += __shfl_xor(s0, off, 32);
        s1 += __shfl_xor(s1, off, 32);
    }
    if (j == 0) {
        out[(size_t)bb * 2 + 0] = s0 + fc_b[0];
        out[(size_t)bb * 2 + 1] = s1 + fc_b[1];
    }
}

extern "C" void kernel_launch(void* const* d_in, const int* in_sizes, int n_in,
                              void* d_out, int out_size, void* d_ws, size_t ws_size,
                              hipStream_t stream)
{
    const float* x    = (const float*)d_in[0];
    const float* W_ih = (const float*)d_in[1];
    const float* W_hh = (const float*)d_in[2];
    const float* b_ih = (const float*)d_in[3];
    const float* b_hh = (const float*)d_in[4];
    const float* fc_w = (const float*)d_in[5];
    const float* fc_b = (const float*)d_in[6];
    float* out = (float*)d_out;

    dim3 grid(512), block(256);
    hipLaunchKernelGGL(gru_fused_kernel, grid, block, 0, stream,
                       x, W_ih, W_hh, b_ih, b_hh, fc_w, fc_b, out);
}

// Round 10
// 167.016 us; speedup vs baseline: 2.8624x; 1.3379x over previous
//
#include <hip/hip_runtime.h>
#include <hip/hip_bf16.h>

// GRU: B=4096, T=512, I=1, H=32, C=2.
// One 32-lane group per batch element (8 groups / 256-thr block, 2048 waves).
// Lane j owns h[j] and W_hh rows {j,32+j,64+j} as 48 int-packed fp16x2 regs.
// vs R8: (1) sigmoid/tanh via raw v_exp_f32+v_rcp_f32 builtins (no IEEE div /
// libm lowering — that was the hidden ~3x VALU inflation), (2) all of x staged
// to LDS once, inner 32-step loop fully unrolled so every x read is a
// ds_read_b32 with an immediate offset (no per-step shuffle/address math).

typedef _Float16 half2v __attribute__((ext_vector_type(2)));

__device__ __forceinline__ float fdot2f(int a, int b, float c) {
    return __builtin_amdgcn_fdot2(__builtin_bit_cast(half2v, a),
                                  __builtin_bit_cast(half2v, b), c, false);
}

__device__ __forceinline__ int pkf16(float lo, float hi) {
    return __builtin_bit_cast(int, __builtin_amdgcn_cvt_pkrtz(lo, hi));
}

// sigmoid(a) = 1/(1+exp(-a)) : v_mul + v_exp + v_add + v_rcp (4 VALU, no div)
__device__ __forceinline__ float sigm(float a) {
    float e = __builtin_amdgcn_exp2f(a * -1.442695041f);
    return __builtin_amdgcn_rcpf(1.0f + e);
}

#define FOR16(M) M(0) M(1) M(2) M(3) M(4) M(5) M(6) M(7) \
                 M(8) M(9) M(10) M(11) M(12) M(13) M(14) M(15)

__global__ __launch_bounds__(256, 1)
void gru_fused_kernel(const float* __restrict__ x,
                      const float* __restrict__ W_ih,
                      const float* __restrict__ W_hh,
                      const float* __restrict__ b_ih,
                      const float* __restrict__ b_hh,
                      const float* __restrict__ fc_w,
                      const float* __restrict__ fc_b,
                      float* __restrict__ out)
{
    const int tid = threadIdx.x;
    const int j   = tid & 31;                      // hidden index this lane owns
    const int g   = tid >> 5;                      // group (batch slot in block)
    const int bb  = blockIdx.x * 8 + g;            // batch element

    __shared__ float xs[8 * 516];                  // all x for this block (pad 4)
    __shared__ unsigned short hbuf[8][32];         // f16 h per group (64B rows)

    // ---- stage the block's entire x [8 batches x 512 t] into LDS ----
    {
        const float* xbase = x + (size_t)blockIdx.x * 8 * 512;
        #pragma unroll
        for (int k = 0; k < 16; ++k) {
            int idx = tid + k * 256;               // coalesced
            int b   = idx >> 9, p = idx & 511;
            xs[b * 516 + p] = xbase[idx];
        }
    }

    // ---- named packed weight registers (48 ints) ----
#define DECLW(p) int wr##p, wz##p, wn##p;
    FOR16(DECLW)
#undef DECLW

    {
        const float4* wrp = reinterpret_cast<const float4*>(W_hh + (j) * 32);
        const float4* wzp = reinterpret_cast<const float4*>(W_hh + (32 + j) * 32);
        const float4* wnp = reinterpret_cast<const float4*>(W_hh + (64 + j) * 32);
#define INITQ(q, p0, p1)                                \
        {                                               \
            float4 a = wrp[q], b = wzp[q], c = wnp[q];  \
            wr##p0 = pkf16(a.x, a.y);                   \
            wr##p1 = pkf16(a.z, a.w);                   \
            wz##p0 = pkf16(b.x, b.y);                   \
            wz##p1 = pkf16(b.z, b.w);                   \
            wn##p0 = pkf16(c.x, c.y);                   \
            wn##p1 = pkf16(c.z, c.w);                   \
        }
        INITQ(0, 0, 1)  INITQ(1, 2, 3)  INITQ(2, 4, 5)  INITQ(3, 6, 7)
        INITQ(4, 8, 9)  INITQ(5, 10, 11) INITQ(6, 12, 13) INITQ(7, 14, 15)
#undef INITQ
    }

    // biases / input weights (I == 1)
    const float br   = b_ih[j]      + b_hh[j];
    const float bz   = b_ih[32 + j] + b_hh[32 + j];
    const float bin  = b_ih[64 + j];
    const float bhn  = b_hh[64 + j];
    const float wihr = W_ih[j];
    const float wihz = W_ih[32 + j];
    const float wihn = W_ih[64 + j];

    float h = 0.0f;
    hbuf[g][j] = 0;                     // f16 +0.0
    __syncthreads();                    // x staging crosses waves

    for (int c = 0; c < 16; ++c) {
        const float* xc = &xs[g * 516 + c * 32];

        #pragma unroll
        for (int tt = 0; tt < 32; ++tt) {
            float xb = xc[tt];                       // ds_read_b32, imm offset

            // read the whole replicated h row (4 x b128 broadcast reads)
            const int4* hp = reinterpret_cast<const int4*>(&hbuf[g][0]);
            int4 A = hp[0], B = hp[1], C = hp[2], D = hp[3];

            float ar = fmaf(xb, wihr, br);
            float az = fmaf(xb, wihz, bz);
            float an = bhn;
            ar = fdot2f(wr0,  A.x, ar); az = fdot2f(wz0,  A.x, az); an = fdot2f(wn0,  A.x, an);
            ar = fdot2f(wr1,  A.y, ar); az = fdot2f(wz1,  A.y, az); an = fdot2f(wn1,  A.y, an);
            ar = fdot2f(wr2,  A.z, ar); az = fdot2f(wz2,  A.z, az); an = fdot2f(wn2,  A.z, an);
            ar = fdot2f(wr3,  A.w, ar); az = fdot2f(wz3,  A.w, az); an = fdot2f(wn3,  A.w, an);
            ar = fdot2f(wr4,  B.x, ar); az = fdot2f(wz4,  B.x, az); an = fdot2f(wn4,  B.x, an);
            ar = fdot2f(wr5,  B.y, ar); az = fdot2f(wz5,  B.y, az); an = fdot2f(wn5,  B.y, an);
            ar = fdot2f(wr6,  B.z, ar); az = fdot2f(wz6,  B.z, az); an = fdot2f(wn6,  B.z, an);
            ar = fdot2f(wr7,  B.w, ar); az = fdot2f(wz7,  B.w, az); an = fdot2f(wn7,  B.w, an);
            ar = fdot2f(wr8,  C.x, ar); az = fdot2f(wz8,  C.x, az); an = fdot2f(wn8,  C.x, an);
            ar = fdot2f(wr9,  C.y, ar); az = fdot2f(wz9,  C.y, az); an = fdot2f(wn9,  C.y, an);
            ar = fdot2f(wr10, C.z, ar); az = fdot2f(wz10, C.z, az); an = fdot2f(wn10, C.z, an);
            ar = fdot2f(wr11, C.w, ar); az = fdot2f(wz11, C.w, az); an = fdot2f(wn11, C.w, an);
            ar = fdot2f(wr12, D.x, ar); az = fdot2f(wz12, D.x, az); an = fdot2f(wn12, D.x, an);
            ar = fdot2f(wr13, D.y, ar); az = fdot2f(wz13, D.y, az); an = fdot2f(wn13, D.y, an);
            ar = fdot2f(wr14, D.z, ar); az = fdot2f(wz14, D.z, az); an = fdot2f(wn14, D.z, an);
            ar = fdot2f(wr15, D.w, ar); az = fdot2f(wz15, D.w, az); an = fdot2f(wn15, D.w, an);

            float r = sigm(ar);
            float z = sigm(az);
            float npre = fmaf(r, an, fmaf(xb, wihn, bin));
            // tanh(a) = 1 - 2/(1+exp(2a)), exp via exp2, div via rcp
            float e2 = __builtin_amdgcn_exp2f(npre * 2.885390082f);
            float t  = __builtin_amdgcn_rcpf(1.0f + e2);
            float n  = fmaf(-2.0f, t, 1.0f);
            h = fmaf(z, h - n, n);       // h = n + z*(h-n)

            // publish new h as f16 for next step's broadcast reads
            hbuf[g][j] = __builtin_bit_cast(unsigned short, (_Float16)h);
        }
    }

    // ---- FC epilogue: out[bb, c] = sum_j h_j * fc_w[c*32+j] + fc_b[c] ----
    float s0 = h * fc_w[j];
    float s1 = h * fc_w[32 + j];
    #pragma unroll
    for (int off = 16; off >= 1; off >>= 1) {
        s0 += __shfl_xor(s0, off, 32);
        s1 += __shfl_xor(s1, off, 32);
    }
    if (j == 0) {
        out[(size_t)bb * 2 + 0] = s0 + fc_b[0];
        out[(size_t)bb * 2 + 1] = s1 + fc_b[1];
    }
}

extern "C" void kernel_launch(void* const* d_in, const int* in_sizes, int n_in,
                              void* d_out, int out_size, void* d_ws, size_t ws_size,
                              hipStream_t stream)
{
    const float* x    = (const float*)d_in[0];
    const float* W_ih = (const float*)d_in[1];
    const float* W_hh = (const float*)d_in[2];
    const float* b_ih = (const float*)d_in[3];
    const float* b_hh = (const float*)d_in[4];
    const float* fc_w = (const float*)d_in[5];
    const float* fc_b = (const float*)d_in[6];
    float* out = (float*)d_out;

    dim3 grid(512), block(256);
    hipLaunchKernelGGL(gru_fused_kernel, grid, block, 0, stream,
                       x, W_ih, W_hh, b_ih, b_hh, fc_w, fc_b, out);
}